// Round 7
// baseline (730.739 us; speedup 1.0000x reference)
//
#include <hip/hip_runtime.h>
#include <stdint.h>

#define E_TOT 500000
#define EB 64
#define NBLK ((E_TOT + EB - 1) / EB)   // 7813
#define SWZ(e) (((e) & 7) << 4)
#define HOFF 32768                     // hbuf byte offset inside smem

using u32x4  = __attribute__((ext_vector_type(4))) unsigned int;
using f32x4  = __attribute__((ext_vector_type(4))) float;
using short8 = __attribute__((ext_vector_type(8))) short;   // 8 bf16 = 4 VGPRs

__device__ __forceinline__ uint32_t f2bf(float x) {
    uint32_t u = __builtin_bit_cast(uint32_t, x);
    return (u + 0x7fffu + ((u >> 16) & 1u)) >> 16;   // RNE, inputs finite
}
__device__ __forceinline__ uint32_t pk2(float a, float b) {
    return f2bf(a) | (f2bf(b) << 16);
}
__device__ __forceinline__ const char* xor64(const char* p) {
    return (const char*)((uintptr_t)p ^ 64);
}

__global__ void prep_weights(const float* __restrict__ W1, const float* __restrict__ W2,
                             unsigned short* __restrict__ w1b, unsigned short* __restrict__ w2b) {
    int t = blockIdx.x * 256 + threadIdx.x;
    int i = t * 4;
    if (i < 131072) {
        float4 f = *reinterpret_cast<const float4*>(W1 + i);
        uint2 u;
        u.x = pk2(f.x, f.y); u.y = pk2(f.z, f.w);
        *reinterpret_cast<uint2*>(w1b + i) = u;
    } else {
        int j = i - 131072;
        float4 f = *reinterpret_cast<const float4*>(W2 + j);
        uint2 u;
        u.x = pk2(f.x, f.y); u.y = pk2(f.z, f.w);
        *reinterpret_cast<uint2*>(w2b + j) = u;
    }
}

// One 2-kk chunk: prefetch next chunk's A-frags (global), then for kk in chunk:
// 4 LDS b-reads (strength-reduced addresses, const offsets) + 8 MFMA.
#define CHUNK(ABASE, MTSTR, LDSOFF, ACC, CUR, NXT, C, LAST)                                  \
  {                                                                                          \
    if (!(LAST)) {                                                                           \
      _Pragma("unroll") for (int kkl = 0; kkl < 2; ++kkl)                                    \
        _Pragma("unroll") for (int mt = 0; mt < 2; ++mt)                                     \
          NXT[kkl][mt] = *reinterpret_cast<const short8*>(                                   \
              (ABASE) + mt * (MTSTR) + (((C) + 1) * 2 + kkl) * 64);                          \
    }                                                                                        \
    _Pragma("unroll") for (int kkl = 0; kkl < 2; ++kkl) {                                    \
      const int kk = (C) * 2 + kkl;                                                          \
      short8 bfr[4];                                                                         \
      _Pragma("unroll") for (int nt = 0; nt < 4; ++nt) {                                     \
        const char* bp = (kk & 1) ? xor64(bx0[nt]) : bx0[nt];                                \
        bfr[nt] = *reinterpret_cast<const short8*>(bp + (LDSOFF) + (kk >> 1) * 128);         \
      }                                                                                      \
      __builtin_amdgcn_s_setprio(1);                                                         \
      _Pragma("unroll") for (int nt = 0; nt < 4; ++nt)                                       \
        _Pragma("unroll") for (int mt = 0; mt < 2; ++mt)                                     \
          ACC[mt][nt] = __builtin_amdgcn_mfma_f32_16x16x32_bf16(                             \
              CUR[kkl][mt], bfr[nt], ACC[mt][nt], 0, 0, 0);                                  \
      __builtin_amdgcn_s_setprio(0);                                                         \
    }                                                                                        \
  }

// Full K=256 phase: preload chunk0, then 4 ping-pong chunks (kk 0..7).
#define PHASE(ABASE, MTSTR, LDSOFF, ACC)                                                     \
  {                                                                                          \
    _Pragma("unroll") for (int kkl = 0; kkl < 2; ++kkl)                                      \
      _Pragma("unroll") for (int mt = 0; mt < 2; ++mt)                                       \
        Aa[kkl][mt] = *reinterpret_cast<const short8*>((ABASE) + mt * (MTSTR) + kkl * 64);   \
    CHUNK(ABASE, MTSTR, LDSOFF, ACC, Aa, Ab, 0, 0)                                           \
    CHUNK(ABASE, MTSTR, LDSOFF, ACC, Ab, Aa, 1, 0)                                           \
    CHUNK(ABASE, MTSTR, LDSOFF, ACC, Aa, Ab, 2, 0)                                           \
    CHUNK(ABASE, MTSTR, LDSOFF, ACC, Ab, Aa, 3, 1)                                           \
  }

// EB=64 edges/block, 8 waves M-split, 2 blocks/CU. smem[0:32K] = X[64][256]bf16
// (swizzled), smem[32K:64K] = h1 half [64 e][256 rows] bf16 (swizzled).
template<bool PREPPED>
__global__ __launch_bounds__(512, 4) void fused_mlp(
    const float* __restrict__ nf,
    const int* __restrict__ eidx,      // int32 per harness contract
    const char* __restrict__ w1p,      // bf16 [512][256] (or f32 W1 if !PREPPED)
    const char* __restrict__ w2p,      // bf16 [256][512] (or f32 W2)
    const float* __restrict__ b1,
    const float* __restrict__ b2,
    const float* __restrict__ w3,
    const float* __restrict__ b3,
    float* __restrict__ out)
{
    __shared__ __align__(16) char smem[65536];
    __shared__ float logit_part[8][EB];

    const int tid  = threadIdx.x;
    const int lane = tid & 63;
    const int wid  = tid >> 6;       // 0..7
    const int hi   = lane >> 4;      // 0..3
    const int lo   = lane & 15;      // 0..15
    const long long e0 = (long long)blockIdx.x * EB;

    // ---- gather + f32->bf16 + swizzled stage: X[e][0:128]=nf[row], [128:256]=nf[col]
    {
        int e    = tid >> 3;          // 0..63
        int side = (tid >> 2) & 1;    // 0=row,1=col
        int q    = tid & 3;           // 32-float quarter
        long long eg = e0 + e;
        int idx = 0;
        if (eg < E_TOT) idx = eidx[(size_t)side * E_TOT + (size_t)eg];
        const float4* src = reinterpret_cast<const float4*>(nf + (size_t)idx * 128 + q * 32);
        char* dstrow = smem + e * 512;
        const int ob = side * 256 + q * 64;
#pragma unroll
        for (int c = 0; c < 4; ++c) {
            float4 f0 = src[2 * c];
            float4 f1 = src[2 * c + 1];
            u32x4 u;
            u[0] = pk2(f0.x, f0.y); u[1] = pk2(f0.z, f0.w);
            u[2] = pk2(f1.x, f1.y); u[3] = pk2(f1.z, f1.w);
            *reinterpret_cast<u32x4*>(dstrow + ((ob + c * 16) ^ SWZ(e))) = u;
        }
    }

    // per-lane strength-reduced LDS b-read bases.
    // addr(kk) = e*512 + ((kk*64 + hi*16) ^ SWZ(e))
    //          = [e*512 + (hi*16 ^ ((e&3)<<4)) + 64*s6b]  (+128*(kk>>1))  for even kk
    //            (same base ^64)                          (+128*(kk>>1))  for odd kk
    const char* bx0[4];
#pragma unroll
    for (int nt = 0; nt < 4; ++nt) {
        int e   = nt * 16 + lo;
        int low = (hi * 16) ^ ((e & 3) << 4);
        int s6  = (e >> 2) & 1;
        bx0[nt] = smem + e * 512 + low + 64 * s6;
    }

    __syncthreads();

    f32x4 acc2[2][4];   // persistent: 32 rows x 64 edges of h2
#pragma unroll
    for (int mt = 0; mt < 2; ++mt)
#pragma unroll
        for (int nt = 0; nt < 4; ++nt)
            acc2[mt][nt] = f32x4{0.f, 0.f, 0.f, 0.f};

    short8 Aa[2][2], Ab[2][2];   // ping-pong A-frag chunks [kkl][mt]

#pragma unroll
    for (int h = 0; h < 2; ++h) {
        // ---- L1 half: rows [h*256 + wid*32, +32) x 64 edges, K=256
        f32x4 acc1[2][4];
#pragma unroll
        for (int mt = 0; mt < 2; ++mt)
#pragma unroll
            for (int nt = 0; nt < 4; ++nt)
                acc1[mt][nt] = f32x4{0.f, 0.f, 0.f, 0.f};

        if constexpr (PREPPED) {
            const char* a1b = w1p + (size_t)(h * 256 + wid * 32 + lo) * 512 + hi * 16;
            PHASE(a1b, (16 * 512), 0, acc1)
        } else {
            const float* W1f = reinterpret_cast<const float*>(w1p);
#pragma unroll
            for (int kk = 0; kk < 8; ++kk) {
                short8 a[2], b[4];
#pragma unroll
                for (int mt = 0; mt < 2; ++mt) {
                    const int row = h * 256 + wid * 32 + mt * 16 + lo;
                    const float* p = W1f + (size_t)row * 256 + kk * 32 + hi * 8;
                    float4 f0 = *reinterpret_cast<const float4*>(p);
                    float4 f1 = *reinterpret_cast<const float4*>(p + 4);
                    u32x4 u;
                    u[0] = pk2(f0.x, f0.y); u[1] = pk2(f0.z, f0.w);
                    u[2] = pk2(f1.x, f1.y); u[3] = pk2(f1.z, f1.w);
                    a[mt] = __builtin_bit_cast(short8, u);
                }
#pragma unroll
                for (int nt = 0; nt < 4; ++nt) {
                    const char* bp = (kk & 1) ? xor64(bx0[nt]) : bx0[nt];
                    b[nt] = *reinterpret_cast<const short8*>(bp + (kk >> 1) * 128);
                }
#pragma unroll
                for (int nt = 0; nt < 4; ++nt)
#pragma unroll
                    for (int mt = 0; mt < 2; ++mt)
                        acc1[mt][nt] = __builtin_amdgcn_mfma_f32_16x16x32_bf16(a[mt], b[nt], acc1[mt][nt], 0, 0, 0);
            }
        }

        // ---- bias+relu -> bf16 -> hbuf (smem+HOFF). rl = wid*32 + mt*16 + hi*4 + r
#pragma unroll
        for (int mt = 0; mt < 2; ++mt) {
            const float4 bias = *reinterpret_cast<const float4*>(b1 + h * 256 + wid * 32 + mt * 16 + hi * 4);
            const int ob = wid * 64 + mt * 32 + hi * 8;   // rl*2 bytes
#pragma unroll
            for (int nt = 0; nt < 4; ++nt) {
                int e = nt * 16 + lo;
                f32x4 v = acc1[mt][nt];
                float r0 = fmaxf(v[0] + bias.x, 0.f);
                float r1 = fmaxf(v[1] + bias.y, 0.f);
                float r2 = fmaxf(v[2] + bias.z, 0.f);
                float r3 = fmaxf(v[3] + bias.w, 0.f);
                uint2 u;
                u.x = pk2(r0, r1); u.y = pk2(r2, r3);
                *reinterpret_cast<uint2*>(smem + HOFF + e * 512 + (ob ^ SWZ(e))) = u;
            }
        }
        __syncthreads();   // hbuf ready

        // ---- L2 partial: rows [wid*32,+32) x 64 edges, K slice [h*256, +256)
        if constexpr (PREPPED) {
            const char* a2b = w2p + (size_t)(wid * 32 + lo) * 1024 + h * 512 + hi * 16;
            PHASE(a2b, (16 * 1024), HOFF, acc2)
        } else {
            const float* W2f = reinterpret_cast<const float*>(w2p);
#pragma unroll
            for (int kk = 0; kk < 8; ++kk) {
                short8 a[2], b[4];
#pragma unroll
                for (int mt = 0; mt < 2; ++mt) {
                    const int row = wid * 32 + mt * 16 + lo;
                    const float* p = W2f + (size_t)row * 512 + h * 256 + kk * 32 + hi * 8;
                    float4 f0 = *reinterpret_cast<const float4*>(p);
                    float4 f1 = *reinterpret_cast<const float4*>(p + 4);
                    u32x4 u;
                    u[0] = pk2(f0.x, f0.y); u[1] = pk2(f0.z, f0.w);
                    u[2] = pk2(f1.x, f1.y); u[3] = pk2(f1.z, f1.w);
                    a[mt] = __builtin_bit_cast(short8, u);
                }
#pragma unroll
                for (int nt = 0; nt < 4; ++nt) {
                    const char* bp = (kk & 1) ? xor64(bx0[nt]) : bx0[nt];
                    b[nt] = *reinterpret_cast<const short8*>(bp + HOFF + (kk >> 1) * 128);
                }
#pragma unroll
                for (int nt = 0; nt < 4; ++nt)
#pragma unroll
                    for (int mt = 0; mt < 2; ++mt)
                        acc2[mt][nt] = __builtin_amdgcn_mfma_f32_16x16x32_bf16(a[mt], b[nt], acc2[mt][nt], 0, 0, 0);
            }
        }
        if (h == 0) __syncthreads();   // all waves done reading hbuf before half-2 overwrite
    }

    // ---- epilogue: bias+relu, store intermediate (f32), logit partials via w3 dot
    {
        float* inter = out + E_TOT;
        float pls[4] = {0.f, 0.f, 0.f, 0.f};
#pragma unroll
        for (int mt = 0; mt < 2; ++mt) {
            const int m = wid * 32 + mt * 16 + hi * 4;
            const float4 bias = *reinterpret_cast<const float4*>(b2 + m);
            const float4 wv   = *reinterpret_cast<const float4*>(w3 + m);
#pragma unroll
            for (int nt = 0; nt < 4; ++nt) {
                long long eg = e0 + nt * 16 + lo;
                f32x4 v = acc2[mt][nt];
                float4 hh;
                hh.x = fmaxf(v[0] + bias.x, 0.f);
                hh.y = fmaxf(v[1] + bias.y, 0.f);
                hh.z = fmaxf(v[2] + bias.z, 0.f);
                hh.w = fmaxf(v[3] + bias.w, 0.f);
                if (eg < E_TOT)
                    *reinterpret_cast<float4*>(inter + (size_t)eg * 256 + m) = hh;
                pls[nt] += hh.x * wv.x + hh.y * wv.y + hh.z * wv.z + hh.w * wv.w;
            }
        }
#pragma unroll
        for (int nt = 0; nt < 4; ++nt) {
            float p = pls[nt];
            p += __shfl_xor(p, 16);
            p += __shfl_xor(p, 32);
            if (hi == 0) logit_part[wid][nt * 16 + lo] = p;
        }
    }
    __syncthreads();
    if (tid < EB) {
        long long eg = e0 + tid;
        if (eg < E_TOT) {
            float s = b3[0];
#pragma unroll
            for (int w = 0; w < 8; ++w) s += logit_part[w][tid];
            out[eg] = s;
        }
    }
}

extern "C" void kernel_launch(void* const* d_in, const int* in_sizes, int n_in,
                              void* d_out, int out_size, void* d_ws, size_t ws_size,
                              hipStream_t stream) {
    const float* nf   = (const float*)d_in[0];
    const int*   eidx = (const int*)d_in[1];
    const float* W1   = (const float*)d_in[2];
    const float* b1   = (const float*)d_in[3];
    const float* W2   = (const float*)d_in[4];
    const float* b2   = (const float*)d_in[5];
    const float* W3   = (const float*)d_in[6];
    const float* b3   = (const float*)d_in[7];
    float* out = (float*)d_out;

    const size_t need = (size_t)(512 * 256 + 256 * 512) * 2;   // 512 KB bf16 weights
    if (ws_size >= need) {
        unsigned short* w1b = (unsigned short*)d_ws;
        unsigned short* w2b = w1b + 512 * 256;
        prep_weights<<<256, 256, 0, stream>>>(W1, W2, w1b, w2b);
        fused_mlp<true><<<NBLK, 512, 0, stream>>>(nf, eidx, (const char*)w1b, (const char*)w2b,
                                                  b1, b2, W3, b3, out);
    } else {
        fused_mlp<false><<<NBLK, 512, 0, stream>>>(nf, eidx, (const char*)W1, (const char*)W2,
                                                   b1, b2, W3, b3, out);
    }
}

// Round 8
// 586.792 us; speedup vs baseline: 1.2453x; 1.2453x over previous
//
#include <hip/hip_runtime.h>
#include <stdint.h>

#define E_TOT 500000
#define EB 64
#define NBLK ((E_TOT + EB - 1) / EB)   // 7813
#define SWZ(e) (((e) & 7) << 4)
#define HOFF 32768                     // hbuf byte offset inside smem

using u32x4  = __attribute__((ext_vector_type(4))) unsigned int;
using f32x4  = __attribute__((ext_vector_type(4))) float;
using short8 = __attribute__((ext_vector_type(8))) short;   // 8 bf16 = 4 VGPRs

__device__ __forceinline__ uint32_t f2bf(float x) {
    uint32_t u = __builtin_bit_cast(uint32_t, x);
    return (u + 0x7fffu + ((u >> 16) & 1u)) >> 16;   // RNE, inputs finite
}
__device__ __forceinline__ uint32_t pk2(float a, float b) {
    return f2bf(a) | (f2bf(b) << 16);
}

__global__ void prep_weights(const float* __restrict__ W1, const float* __restrict__ W2,
                             unsigned short* __restrict__ w1b, unsigned short* __restrict__ w2b) {
    int t = blockIdx.x * 256 + threadIdx.x;
    int i = t * 4;
    if (i < 131072) {
        float4 f = *reinterpret_cast<const float4*>(W1 + i);
        uint2 u;
        u.x = pk2(f.x, f.y); u.y = pk2(f.z, f.w);
        *reinterpret_cast<uint2*>(w1b + i) = u;
    } else {
        int j = i - 131072;
        float4 f = *reinterpret_cast<const float4*>(W2 + j);
        uint2 u;
        u.x = pk2(f.x, f.y); u.y = pk2(f.z, f.w);
        *reinterpret_cast<uint2*>(w2b + j) = u;
    }
}

// One 2-kk chunk: prefetch next chunk's 8 A-frags (global, L2-hot), then for
// each kk in chunk: 4 LDS b-reads (strength-reduced addr) + 16 MFMA.
#define CHUNK(ABASE, MTSTR, LDSOFF, ACC, CUR, NXT, C, LAST)                                  \
  {                                                                                          \
    if (!(LAST)) {                                                                           \
      _Pragma("unroll") for (int kkl = 0; kkl < 2; ++kkl)                                    \
        _Pragma("unroll") for (int mt = 0; mt < 4; ++mt)                                     \
          NXT[kkl][mt] = *reinterpret_cast<const short8*>(                                   \
              (ABASE) + mt * (MTSTR) + (((C) + 1) * 2 + kkl) * 64);                          \
    }                                                                                        \
    _Pragma("unroll") for (int kkl = 0; kkl < 2; ++kkl) {                                    \
      const int kk = (C) * 2 + kkl;                                                          \
      short8 bfr[4];                                                                         \
      _Pragma("unroll") for (int nt = 0; nt < 4; ++nt) {                                     \
        const int boff = ((kk & 1) ? (bx0[nt] ^ 64) : bx0[nt]) + (LDSOFF) + (kk >> 1) * 128; \
        bfr[nt] = *reinterpret_cast<const short8*>(smem + boff);                             \
      }                                                                                      \
      _Pragma("unroll") for (int nt = 0; nt < 4; ++nt)                                       \
        _Pragma("unroll") for (int mt = 0; mt < 4; ++mt)                                     \
          ACC[mt][nt] = __builtin_amdgcn_mfma_f32_16x16x32_bf16(                             \
              CUR[kkl][mt], bfr[nt], ACC[mt][nt], 0, 0, 0);                                  \
    }                                                                                        \
  }

// Full K=256 phase (8 kk): preload chunk0, then 4 ping-pong chunks.
#define PHASE(ABASE, MTSTR, LDSOFF, ACC)                                                     \
  {                                                                                          \
    _Pragma("unroll") for (int kkl = 0; kkl < 2; ++kkl)                                      \
      _Pragma("unroll") for (int mt = 0; mt < 4; ++mt)                                       \
        Aa[kkl][mt] = *reinterpret_cast<const short8*>((ABASE) + mt * (MTSTR) + kkl * 64);   \
    CHUNK(ABASE, MTSTR, LDSOFF, ACC, Aa, Ab, 0, 0)                                           \
    CHUNK(ABASE, MTSTR, LDSOFF, ACC, Ab, Aa, 1, 0)                                           \
    CHUNK(ABASE, MTSTR, LDSOFF, ACC, Aa, Ab, 2, 0)                                           \
    CHUNK(ABASE, MTSTR, LDSOFF, ACC, Ab, Aa, 3, 1)                                           \
  }

// EB=64 edges/block, 4 waves (256 thr), M=64 rows/wave, 2 blocks/CU.
// launch_bounds(256,2) -> 256 unified regs/wave: acc 128 AGPR + prefetch fits.
template<bool PREPPED>
__global__ __launch_bounds__(256, 2) void fused_mlp(
    const float* __restrict__ nf,
    const int* __restrict__ eidx,      // int32 per harness contract
    const char* __restrict__ w1p,      // bf16 [512][256] (or f32 W1 if !PREPPED)
    const char* __restrict__ w2p,      // bf16 [256][512] (or f32 W2)
    const float* __restrict__ b1,
    const float* __restrict__ b2,
    const float* __restrict__ w3,
    const float* __restrict__ b3,
    float* __restrict__ out)
{
    // smem[0:32K] = X[64][256] bf16 (swizzled rows)
    // smem[32K:64K] = h1 half [64 e][256 rows] bf16 (swizzled)
    __shared__ __align__(16) char smem[65536];
    __shared__ float logit_part[4][EB];

    const int tid  = threadIdx.x;
    const int lane = tid & 63;
    const int wid  = tid >> 6;       // 0..3
    const int hi   = lane >> 4;      // 0..3
    const int lo   = lane & 15;      // 0..15
    const long long e0 = (long long)blockIdx.x * EB;

    // ---- gather + f32->bf16 + swizzled stage: X[e][0:128]=nf[row], [128:256]=nf[col]
    {
        int e    = tid >> 2;          // 0..63
        int side = (tid >> 1) & 1;    // 0=row,1=col
        int half = tid & 1;           // 64-float half
        long long eg = e0 + e;
        int idx = 0;
        if (eg < E_TOT) idx = eidx[(size_t)side * E_TOT + (size_t)eg];
        const float4* src = reinterpret_cast<const float4*>(nf + (size_t)idx * 128 + half * 64);
        char* dstrow = smem + e * 512;
        const int ob = side * 256 + half * 128;
#pragma unroll
        for (int c = 0; c < 8; ++c) {
            float4 f0 = src[2 * c];
            float4 f1 = src[2 * c + 1];
            u32x4 u;
            u[0] = pk2(f0.x, f0.y); u[1] = pk2(f0.z, f0.w);
            u[2] = pk2(f1.x, f1.y); u[3] = pk2(f1.z, f1.w);
            *reinterpret_cast<u32x4*>(dstrow + ((ob + c * 16) ^ SWZ(e))) = u;
        }
    }

    // strength-reduced LDS b-read base offsets (32-bit).
    // addr(kk) = e*512 + ((kk*64 + hi*16) ^ SWZ(e))
    //          = bx0 (+128*(kk>>1)), with ^64 for odd kk.
    int bx0[4];
#pragma unroll
    for (int nt = 0; nt < 4; ++nt) {
        int e   = nt * 16 + lo;
        int low = (hi * 16) ^ ((e & 3) << 4);
        int s6  = (e >> 2) & 1;
        bx0[nt] = e * 512 + low + 64 * s6;
    }

    __syncthreads();

    f32x4 acc2[4][4];   // persistent: 64 rows x 64 edges of h2
#pragma unroll
    for (int mt = 0; mt < 4; ++mt)
#pragma unroll
        for (int nt = 0; nt < 4; ++nt)
            acc2[mt][nt] = f32x4{0.f, 0.f, 0.f, 0.f};

    short8 Aa[2][4], Ab[2][4];   // ping-pong A-frag chunks [kkl][mt]

#pragma unroll
    for (int h = 0; h < 2; ++h) {
        // ---- L1 half: rows [h*256 + wid*64, +64) x 64 edges, K=256
        f32x4 acc1[4][4];
#pragma unroll
        for (int mt = 0; mt < 4; ++mt)
#pragma unroll
            for (int nt = 0; nt < 4; ++nt)
                acc1[mt][nt] = f32x4{0.f, 0.f, 0.f, 0.f};

        if constexpr (PREPPED) {
            const char* a1b = w1p + (size_t)(h * 256 + wid * 64 + lo) * 512 + hi * 16;
            PHASE(a1b, (16 * 512), 0, acc1)
        } else {
            const float* W1f = reinterpret_cast<const float*>(w1p);
#pragma unroll
            for (int kk = 0; kk < 8; ++kk) {
                short8 a[4], b[4];
#pragma unroll
                for (int mt = 0; mt < 4; ++mt) {
                    const int row = h * 256 + wid * 64 + mt * 16 + lo;
                    const float* p = W1f + (size_t)row * 256 + kk * 32 + hi * 8;
                    float4 f0 = *reinterpret_cast<const float4*>(p);
                    float4 f1 = *reinterpret_cast<const float4*>(p + 4);
                    u32x4 u;
                    u[0] = pk2(f0.x, f0.y); u[1] = pk2(f0.z, f0.w);
                    u[2] = pk2(f1.x, f1.y); u[3] = pk2(f1.z, f1.w);
                    a[mt] = __builtin_bit_cast(short8, u);
                }
#pragma unroll
                for (int nt = 0; nt < 4; ++nt) {
                    const int boff = ((kk & 1) ? (bx0[nt] ^ 64) : bx0[nt]) + (kk >> 1) * 128;
                    b[nt] = *reinterpret_cast<const short8*>(smem + boff);
                }
#pragma unroll
                for (int nt = 0; nt < 4; ++nt)
#pragma unroll
                    for (int mt = 0; mt < 4; ++mt)
                        acc1[mt][nt] = __builtin_amdgcn_mfma_f32_16x16x32_bf16(a[mt], b[nt], acc1[mt][nt], 0, 0, 0);
            }
        }

        // ---- bias+relu -> bf16 -> hbuf. local row rl = wid*64 + mt*16 + hi*4 + r
#pragma unroll
        for (int mt = 0; mt < 4; ++mt) {
            const float4 bias = *reinterpret_cast<const float4*>(b1 + h * 256 + wid * 64 + mt * 16 + hi * 4);
            const int ob = wid * 128 + mt * 32 + hi * 8;   // rl*2 bytes
#pragma unroll
            for (int nt = 0; nt < 4; ++nt) {
                int e = nt * 16 + lo;
                f32x4 v = acc1[mt][nt];
                float r0 = fmaxf(v[0] + bias.x, 0.f);
                float r1 = fmaxf(v[1] + bias.y, 0.f);
                float r2 = fmaxf(v[2] + bias.z, 0.f);
                float r3 = fmaxf(v[3] + bias.w, 0.f);
                uint2 u;
                u.x = pk2(r0, r1); u.y = pk2(r2, r3);
                *reinterpret_cast<uint2*>(smem + HOFF + e * 512 + (ob ^ SWZ(e))) = u;
            }
        }
        __syncthreads();   // hbuf ready

        // ---- L2 partial: rows [wid*64,+64) x 64 edges, K slice [h*256, +256)
        if constexpr (PREPPED) {
            const char* a2b = w2p + (size_t)(wid * 64 + lo) * 1024 + h * 512 + hi * 16;
            PHASE(a2b, (16 * 1024), HOFF, acc2)
        } else {
            const float* W2f = reinterpret_cast<const float*>(w2p);
#pragma unroll
            for (int kk = 0; kk < 8; ++kk) {
                short8 a[4], b[4];
#pragma unroll
                for (int mt = 0; mt < 4; ++mt) {
                    const int row = wid * 64 + mt * 16 + lo;
                    const float* p = W2f + (size_t)row * 512 + h * 256 + kk * 32 + hi * 8;
                    float4 f0 = *reinterpret_cast<const float4*>(p);
                    float4 f1 = *reinterpret_cast<const float4*>(p + 4);
                    u32x4 u;
                    u[0] = pk2(f0.x, f0.y); u[1] = pk2(f0.z, f0.w);
                    u[2] = pk2(f1.x, f1.y); u[3] = pk2(f1.z, f1.w);
                    a[mt] = __builtin_bit_cast(short8, u);
                }
#pragma unroll
                for (int nt = 0; nt < 4; ++nt) {
                    const int boff = ((kk & 1) ? (bx0[nt] ^ 64) : bx0[nt]) + HOFF + (kk >> 1) * 128;
                    b[nt] = *reinterpret_cast<const short8*>(smem + boff);
                }
#pragma unroll
                for (int nt = 0; nt < 4; ++nt)
#pragma unroll
                    for (int mt = 0; mt < 4; ++mt)
                        acc2[mt][nt] = __builtin_amdgcn_mfma_f32_16x16x32_bf16(a[mt], b[nt], acc2[mt][nt], 0, 0, 0);
            }
        }
        if (h == 0) __syncthreads();   // all waves done reading hbuf before half-2 overwrite
    }

    // ---- epilogue: bias+relu, store intermediate (f32), logit partials via w3 dot
    {
        float* inter = out + E_TOT;
        float pls[4] = {0.f, 0.f, 0.f, 0.f};
#pragma unroll
        for (int mt = 0; mt < 4; ++mt) {
            const int m = wid * 64 + mt * 16 + hi * 4;
            const float4 bias = *reinterpret_cast<const float4*>(b2 + m);
            const float4 wv   = *reinterpret_cast<const float4*>(w3 + m);
#pragma unroll
            for (int nt = 0; nt < 4; ++nt) {
                long long eg = e0 + nt * 16 + lo;
                f32x4 v = acc2[mt][nt];
                float4 hh;
                hh.x = fmaxf(v[0] + bias.x, 0.f);
                hh.y = fmaxf(v[1] + bias.y, 0.f);
                hh.z = fmaxf(v[2] + bias.z, 0.f);
                hh.w = fmaxf(v[3] + bias.w, 0.f);
                if (eg < E_TOT)
                    *reinterpret_cast<float4*>(inter + (size_t)eg * 256 + m) = hh;
                pls[nt] += hh.x * wv.x + hh.y * wv.y + hh.z * wv.z + hh.w * wv.w;
            }
        }
#pragma unroll
        for (int nt = 0; nt < 4; ++nt) {
            float p = pls[nt];
            p += __shfl_xor(p, 16);
            p += __shfl_xor(p, 32);
            if (hi == 0) logit_part[wid][nt * 16 + lo] = p;
        }
    }
    __syncthreads();
    if (tid < EB) {
        long long eg = e0 + tid;
        if (eg < E_TOT) {
            float s = b3[0];
#pragma unroll
            for (int w = 0; w < 4; ++w) s += logit_part[w][tid];
            out[eg] = s;
        }
    }
}

extern "C" void kernel_launch(void* const* d_in, const int* in_sizes, int n_in,
                              void* d_out, int out_size, void* d_ws, size_t ws_size,
                              hipStream_t stream) {
    const float* nf   = (const float*)d_in[0];
    const int*   eidx = (const int*)d_in[1];
    const float* W1   = (const float*)d_in[2];
    const float* b1   = (const float*)d_in[3];
    const float* W2   = (const float*)d_in[4];
    const float* b2   = (const float*)d_in[5];
    const float* W3   = (const float*)d_in[6];
    const float* b3   = (const float*)d_in[7];
    float* out = (float*)d_out;

    const size_t need = (size_t)(512 * 256 + 256 * 512) * 2;   // 512 KB bf16 weights
    if (ws_size >= need) {
        unsigned short* w1b = (unsigned short*)d_ws;
        unsigned short* w2b = w1b + 512 * 256;
        prep_weights<<<256, 256, 0, stream>>>(W1, W2, w1b, w2b);
        fused_mlp<true><<<NBLK, 256, 0, stream>>>(nf, eidx, (const char*)w1b, (const char*)w2b,
                                                  b1, b2, W3, b3, out);
    } else {
        fused_mlp<false><<<NBLK, 256, 0, stream>>>(nf, eidx, (const char*)W1, (const char*)W2,
                                                   b1, b2, W3, b3, out);
    }
}